// Round 8
// baseline (81.760 us; speedup 1.0000x reference)
//
#include <hip/hip_runtime.h>
#include <hip/hip_bf16.h>

// Problem constants (fixed by the reference setup)
#define B_     4
#define C_     256
#define H_     64
#define W_     64
#define N_     256
#define HW_    (H_ * W_)          // 4096
#define SS_    0.0625f
#define TSTD_  0.1f

__device__ __forceinline__ unsigned short f2bf(float f) {   // RNE f32->bf16
    unsigned u; __builtin_memcpy(&u, &f, 4);
    u += 0x7FFFu + ((u >> 16) & 1u);
    return (unsigned short)(u >> 16);
}
__device__ __forceinline__ float blo(unsigned u) {          // low bf16 -> f32
    unsigned v = u << 16; float f; __builtin_memcpy(&f, &v, 4); return f;
}
__device__ __forceinline__ float bhi(unsigned u) {          // high bf16 -> f32
    unsigned v = u & 0xFFFF0000u; float f; __builtin_memcpy(&f, &v, 4); return f;
}

// -------- Pass 1: transpose (B,C,H,W) f32 -> (B,H*W,C) bf16 --------
__global__ __launch_bounds__(256) void transpose_bchw_to_bpc_bf16(
    const float* __restrict__ in, unsigned short* __restrict__ out) {
    __shared__ float tile[64][65];   // [p_local][c_local], +1 pad
    const int b  = blockIdx.z;
    const int c0 = blockIdx.y * 64;
    const int p0 = blockIdx.x * 64;
    const int tid = threadIdx.x;
    const int hi = tid >> 4;         // 0..15
    const int lo = tid & 15;         // 0..15

#pragma unroll
    for (int j = 0; j < 4; ++j) {
        const int c = hi + j * 16;   // c_local
        const float4 v = *(const float4*)&in[(size_t)(b * C_ + c0 + c) * HW_ + p0 + lo * 4];
        tile[lo * 4 + 0][c] = v.x;
        tile[lo * 4 + 1][c] = v.y;
        tile[lo * 4 + 2][c] = v.z;
        tile[lo * 4 + 3][c] = v.w;
    }
    __syncthreads();
#pragma unroll
    for (int j = 0; j < 4; ++j) {
        const int p = hi + j * 16;   // p_local
        ushort4 o;
        o.x = f2bf(tile[p][lo * 4 + 0]);
        o.y = f2bf(tile[p][lo * 4 + 1]);
        o.z = f2bf(tile[p][lo * 4 + 2]);
        o.w = f2bf(tile[p][lo * 4 + 3]);
        *(ushort4*)&out[(size_t)(b * HW_ + p0 + p) * C_ + c0 + lo * 4] = o;
    }
}

// -------- Pass 2: one block per ROI (1024 threads = 16 waves).
// Phase A: 49 threads build per-bin lists of (elem-offset, weight/count),
//          ALWAYS padded to 16 entries (pads -> offset 0, L1-hot).
// Phase B: wave per bin (lane = 4 channels): fully-unrolled 16 independent
//          uint2 (4x bf16) loads issued back-to-back -> single latency
//          exposure per bin; then one FMA block.
// Phase C: stride-1 b128 LDS reads -> fully coalesced f32 dwordx4 stores.
__global__ __launch_bounds__(1024) void deform_roi_pool_kernel(
    const unsigned short* __restrict__ tdata,  // (B, H*W, C) bf16
    const float* __restrict__ rois,    // (N, 5)
    const float* __restrict__ offset,  // (N, 2, 7, 7)
    float* __restrict__ out) {         // (N, C, 7, 7)
    __shared__ float lout[C_ * 49];    // [c][bl]  50.2 KB, exact output layout
    __shared__ int   coff[49 * 16];    // cell element-offsets (16/bin, 0-padded)
    __shared__ float cwt [49 * 16];    // cell weights (inv-count folded, 0-padded)

    const int n    = blockIdx.x;
    const int tid  = threadIdx.x;
    const int lane = tid & 63;
    const int wv   = tid >> 6;        // wave 0..15
    const int c4   = lane * 4;        // 4 channels per lane

    const int b = (int)rois[n * 5 + 0];

    // ---- Phase A ----
    if (tid < 49) {
        const float x1  = rintf(rois[n * 5 + 1]) * SS_ - 0.5f;
        const float y1  = rintf(rois[n * 5 + 2]) * SS_ - 0.5f;
        const float x2  = (rintf(rois[n * 5 + 3]) + 1.0f) * SS_ - 0.5f;
        const float y2  = (rintf(rois[n * 5 + 4]) + 1.0f) * SS_ - 0.5f;
        const float roi_w = fmaxf(x2 - x1, 0.1f);
        const float roi_h = fmaxf(y2 - y1, 0.1f);
        const float bin_w = roi_w / 7.0f;
        const float bin_h = roi_h / 7.0f;
        const float sub_w = bin_w / 4.0f;
        const float sub_h = bin_h / 4.0f;

        const int bin = tid;
        const int ph  = bin / 7;
        const int pw  = bin - ph * 7;
        const float tx = offset[(n * 2 + 0) * 49 + bin] * TSTD_;
        const float ty = offset[(n * 2 + 1) * 49 + bin] * TSTD_;
        const float wst = (float)pw * bin_w + x1 + tx * roi_w;
        const float hst = (float)ph * bin_h + y1 + ty * roi_h;

        float rws[4] = {0.f, 0.f, 0.f, 0.f};
        float cws[4] = {0.f, 0.f, 0.f, 0.f};
        int ybase = -100, xbase = -100, nvh = 0, nvw = 0;
#pragma unroll
        for (int s = 0; s < 4; ++s) {
            const float h = hst + (float)s * sub_h;
            if (h >= -0.5f && h <= (float)H_ - 0.5f) {
                ++nvh;
                const float hf  = fminf(fmaxf(h, 0.f), (float)(H_ - 1));
                const float y0f = floorf(hf);
                const float dy  = hf - y0f;
                const int   y0  = (int)y0f;
                if (ybase < -50) ybase = y0;
                const int idx = y0 - ybase;            // 0..2 (span <= 1.3 px)
                rws[0] += (idx == 0) ? (1.f - dy) : 0.f;
                rws[1] += (idx == 1) ? (1.f - dy) : ((idx == 0) ? dy : 0.f);
                rws[2] += (idx == 2) ? (1.f - dy) : ((idx == 1) ? dy : 0.f);
                rws[3] += (idx == 2) ? dy : 0.f;
            }
            const float w = wst + (float)s * sub_w;
            if (w >= -0.5f && w <= (float)W_ - 0.5f) {
                ++nvw;
                const float wf  = fminf(fmaxf(w, 0.f), (float)(W_ - 1));
                const float x0f = floorf(wf);
                const float dx  = wf - x0f;
                const int   x0  = (int)x0f;
                if (xbase < -50) xbase = x0;
                const int idx = x0 - xbase;
                cws[0] += (idx == 0) ? (1.f - dx) : 0.f;
                cws[1] += (idx == 1) ? (1.f - dx) : ((idx == 0) ? dx : 0.f);
                cws[2] += (idx == 2) ? (1.f - dx) : ((idx == 1) ? dx : 0.f);
                cws[3] += (idx == 2) ? dx : 0.f;
            }
        }
        const int count = nvh * nvw;
        const float inv = (count > 0) ? (1.0f / (float)count) : 0.0f;
        if (xbase < 0) xbase = 0;
        if (ybase < 0) ybase = 0;

        int m = 0;
#pragma unroll
        for (int r = 0; r < 4; ++r) {
            if (rws[r] != 0.f) {
                const int rowoff = (ybase + r) * W_;
#pragma unroll
                for (int cc = 0; cc < 4; ++cc) {
                    if (cws[cc] != 0.f) {
                        coff[bin * 16 + m] = (rowoff + xbase + cc) * C_;
                        cwt [bin * 16 + m] = rws[r] * cws[cc] * inv;
                        ++m;
                    }
                }
            }
        }
        while (m < 16) { coff[bin * 16 + m] = 0; cwt[bin * 16 + m] = 0.f; ++m; }
    }
    __syncthreads();

    // ---- Phase B: 16 independent loads per bin, fully unrolled ----
    const unsigned short* __restrict__ base = tdata + (size_t)b * HW_ * C_ + c4;
    for (int bl = wv; bl < 49; bl += 16) {
        uint2 d[16];
        float w[16];
#pragma unroll
        for (int k = 0; k < 16; ++k) {
            const int o = coff[bl * 16 + k];
            w[k] = cwt[bl * 16 + k];
            d[k] = *(const uint2*)(base + o);
        }
        float4 acc = make_float4(0.f, 0.f, 0.f, 0.f);
#pragma unroll
        for (int k = 0; k < 16; ++k) {
            acc.x += w[k] * blo(d[k].x);
            acc.y += w[k] * bhi(d[k].x);
            acc.z += w[k] * blo(d[k].y);
            acc.w += w[k] * bhi(d[k].y);
        }
        // scatter into exact output layout [c][bl]
        lout[(c4 + 0) * 49 + bl] = acc.x;
        lout[(c4 + 1) * 49 + bl] = acc.y;
        lout[(c4 + 2) * 49 + bl] = acc.z;
        lout[(c4 + 3) * 49 + bl] = acc.w;
    }
    __syncthreads();

    // ---- Phase C: stride-1 b128 LDS reads -> fully coalesced dwordx4 stores ----
    float* __restrict__ outn = out + (size_t)n * (C_ * 49);
    for (int i = tid; i < (C_ * 49) / 4; i += 1024) {
        const float4 o = *(const float4*)&lout[i * 4];
        *(float4*)(outn + (size_t)i * 4) = o;
    }
}

extern "C" void kernel_launch(void* const* d_in, const int* in_sizes, int n_in,
                              void* d_out, int out_size, void* d_ws, size_t ws_size,
                              hipStream_t stream) {
    const float* data   = (const float*)d_in[0];
    const float* rois   = (const float*)d_in[1];
    const float* offset = (const float*)d_in[2];
    float* out = (float*)d_out;
    unsigned short* tdata = (unsigned short*)d_ws;   // B*C*H*W*2 = 8 MiB of ws

    dim3 tg(HW_ / 64, C_ / 64, B_);   // (64, 4, 4)
    transpose_bchw_to_bpc_bf16<<<tg, 256, 0, stream>>>(data, tdata);

    deform_roi_pool_kernel<<<N_, 1024, 0, stream>>>(tdata, rois, offset, out);
}